// Round 2
// baseline (8365.583 us; speedup 1.0000x reference)
//
#include <hip/hip_runtime.h>
#include <cstdint>
#include <cstddef>

// ---------------------------------------------------------------------------
// Problem constants
// ---------------------------------------------------------------------------
#define BB 32      // batch
#define TT 512     // seq len
#define DD 512     // emb dim
#define HH 512     // lstm size
#define FOURH 2048
#define DIRS 10    // 5 stacks x {fw,bw}

typedef unsigned short u16;
typedef __attribute__((ext_vector_type(8))) short short8;   // 8 x bf16 (4 VGPRs)
typedef __attribute__((ext_vector_type(4))) float f32x4;    // MFMA accum

__device__ __forceinline__ u16 f2b(float f) {
    union { float f; unsigned u; } v; v.f = f;
    unsigned u = v.u;
    u = (u + 0x7FFFu + ((u >> 16) & 1u)) >> 16;   // RNE
    return (u16)u;
}
__device__ __forceinline__ float b2f(u16 b) {
    union { unsigned u; float f; } v; v.u = ((unsigned)b) << 16;
    return v.f;
}
__device__ __forceinline__ float sigm(float x) { return 1.f / (1.f + __expf(-x)); }
__device__ __forceinline__ float tanh_(float x) { return 1.f - 2.f / (1.f + __expf(2.f * x)); }
__device__ __forceinline__ f32x4 fzero() { f32x4 z = {0.f, 0.f, 0.f, 0.f}; return z; }

// ---------------------------------------------------------------------------
// K1: x fp32 -> bf16
// ---------------------------------------------------------------------------
__global__ void k_convx(const float* __restrict__ X, u16* __restrict__ XB) {
    int i = blockIdx.x * 256 + threadIdx.x;
    if (i >= (BB * TT * DD) / 4) return;
    float4 v = ((const float4*)X)[i];
    unsigned lo = (unsigned)f2b(v.x) | ((unsigned)f2b(v.y) << 16);
    unsigned hi = (unsigned)f2b(v.z) | ((unsigned)f2b(v.w) << 16);
    uint2 o; o.x = lo; o.y = hi;
    ((uint2*)XB)[i] = o;
}

// ---------------------------------------------------------------------------
// K2: build WT[d][n][k] = W_src[s][k][n] (bf16), LDS-tiled transpose.
// grid (32 ktiles, 64 ntiles, 10 dirs), block 256
// ---------------------------------------------------------------------------
__global__ void k_wt(const float* __restrict__ Wf, const float* __restrict__ Wb,
                     u16* __restrict__ WT) {
    int d = blockIdx.z, s = d >> 1;
    const float* src = (d & 1) ? Wb : Wf;   // [5][1024][2048]
    __shared__ float tile[32][33];
    int tx = threadIdx.x & 31, ty = threadIdx.x >> 5;   // ty 0..7
    int kt = blockIdx.x, nt = blockIdx.y;
#pragma unroll
    for (int r = 0; r < 4; r++) {
        int k = kt * 32 + ty + r * 8, n = nt * 32 + tx;
        tile[ty + r * 8][tx] = src[((size_t)s * 1024 + k) * 2048 + n];
    }
    __syncthreads();
#pragma unroll
    for (int r = 0; r < 4; r++) {
        int n = nt * 32 + ty + r * 8, k = kt * 32 + tx;
        WT[((size_t)d * 2048 + n) * 1024 + k] = f2b(tile[tx][ty + r * 8]);
    }
}

// ---------------------------------------------------------------------------
// K3: build head weight WBT[64 c][5120 k] bf16 + bias B64[64].
// ---------------------------------------------------------------------------
__global__ void k_wbt(const float* W1, const float* W2, const float* W3, const float* W4,
                      const float* b1, const float* b2, const float* b3, const float* b4,
                      u16* __restrict__ WBT, float* __restrict__ B64) {
    int idx = blockIdx.x * 256 + threadIdx.x;
    const int off[4] = {0, 17, 26, 51};
    const int tg[4]  = {17, 9, 25, 13};
    if (idx < 64) {
        int c = idx;
        int ti = (c < 17) ? 0 : (c < 26) ? 1 : (c < 51) ? 2 : 3;
        const float* bbp[4] = {b1, b2, b3, b4};
        B64[c] = bbp[ti][c - off[ti]];
    }
    if (idx >= 64 * 5120) return;
    int c = idx / 5120, k = idx % 5120;
    int ti = (c < 17) ? 0 : (c < 26) ? 1 : (c < 51) ? 2 : 3;
    const float* Ws[4] = {W1, W2, W3, W4};
    int tag = c - off[ti];
    float v;
    if (k < 4096) {
        int i = k >> 10, kk = k & 1023;
        v = (i == ti) ? Ws[ti][(size_t)kk * tg[ti] + tag] : 0.f;
    } else {
        int kk = k - 4096;
        v = Ws[ti][(size_t)(1024 + kk) * tg[ti] + tag];
    }
    WBT[(size_t)c * 5120 + k] = f2b(v);
}

// ---------------------------------------------------------------------------
// K4: chunk pre-GEMM: P[d][tt][b][n] = xrow(d,b,t0+tt) @ Wx[d] + bias[d][n]
// xrow = x[b][t] fw, x[b][ridx(b,t)] bw (reverse_sequence fused as gather).
// 128x128 tile, BK=64, bf16 MFMA 16x16x32. grid (16, chunk/4, 10), block 256.
// ---------------------------------------------------------------------------
__global__ __launch_bounds__(256) void k_pregemm(
    const u16* __restrict__ XB, const u16* __restrict__ WT,
    const float* __restrict__ bfw, const float* __restrict__ bbw,
    const int* __restrict__ lens, u16* __restrict__ P, int t0, int chunk)
{
    int nt = blockIdx.x, mt = blockIdx.y, d = blockIdx.z;
    int s = d >> 1, isbw = d & 1;
    int tid = threadIdx.x, w = tid >> 6, lane = tid & 63, quad = lane >> 4, l15 = lane & 15;
    int mh = w & 1, nh = w >> 1;
    __shared__ u16 lA[128 * 64];
    __shared__ u16 lB[128 * 64];
    const float* bias = (isbw ? bbw : bfw) + (size_t)s * 2048;

    f32x4 acc[4][4];
#pragma unroll
    for (int mi = 0; mi < 4; mi++)
#pragma unroll
        for (int ni = 0; ni < 4; ni++) acc[mi][ni] = fzero();

    for (int kk0 = 0; kk0 < 512; kk0 += 64) {
#pragma unroll
        for (int p = 0; p < 4; p++) {
            int g = p * 256 + tid;          // granule 0..1023 (16B each)
            int row = g >> 3, c16 = g & 7;
            int grow = mt * 128 + row, ttl = grow >> 5, b = grow & 31;
            int t = t0 + ttl, srcT = t;
            if (isbw) { int lb = lens[b]; srcT = (t < lb) ? (lb - 1 - t) : t; }
            const u16* ga = XB + ((size_t)b * TT + srcT) * DD + kk0 + c16 * 8;
            ((uint4*)lA)[g] = *(const uint4*)ga;
            int nrow = nt * 128 + row;
            const u16* gb = WT + ((size_t)d * 2048 + nrow) * 1024 + kk0 + c16 * 8;
            ((uint4*)lB)[g] = *(const uint4*)gb;
        }
        __syncthreads();
#pragma unroll
        for (int ks = 0; ks < 2; ks++) {
            short8 af[4], bf[4];
#pragma unroll
            for (int mi = 0; mi < 4; mi++)
                af[mi] = *(const short8*)(lA + (mh * 64 + mi * 16 + l15) * 64 + ks * 32 + quad * 8);
#pragma unroll
            for (int ni = 0; ni < 4; ni++)
                bf[ni] = *(const short8*)(lB + (nh * 64 + ni * 16 + l15) * 64 + ks * 32 + quad * 8);
#pragma unroll
            for (int mi = 0; mi < 4; mi++)
#pragma unroll
                for (int ni = 0; ni < 4; ni++)
                    acc[mi][ni] = __builtin_amdgcn_mfma_f32_16x16x32_bf16(af[mi], bf[ni], acc[mi][ni], 0, 0, 0);
        }
        __syncthreads();
    }
#pragma unroll
    for (int ni = 0; ni < 4; ni++) {
        int n = nt * 128 + nh * 64 + ni * 16 + l15;
        float bv = bias[n];
#pragma unroll
        for (int mi = 0; mi < 4; mi++) {
#pragma unroll
            for (int r = 0; r < 4; r++) {
                int mlocal = mh * 64 + mi * 16 + quad * 4 + r;
                int grow = mt * 128 + mlocal, ttl = grow >> 5, b = grow & 31;
                P[(((size_t)d * chunk + ttl) * BB + b) * FOURH + n] = f2b(acc[mi][ni][r] + bv);
            }
        }
    }
}

// ---------------------------------------------------------------------------
// K5: one recurrent timestep for all 10 directions.
// grid 160 = 10 dirs x 16 WGs (32 hidden units each), block 512 (8 waves).
// ---------------------------------------------------------------------------
__global__ __launch_bounds__(512) void k_step(
    const u16* __restrict__ WT, const u16* __restrict__ P,
    u16* __restrict__ Hbuf, float* __restrict__ Cst, u16* __restrict__ OUTS,
    const int* __restrict__ lens, int t, int tt, int chunk)
{
    int blk = blockIdx.x, d = blk >> 4, jj = blk & 15;
    int s = d >> 1, isbw = d & 1;
    int tid = threadIdx.x, w = tid >> 6, lane = tid & 63, quad = lane >> 4, l15 = lane & 15;
    int mtile = w & 1, nhalf = (w >> 1) & 1, khalf = w >> 2;
    const size_t HSZ = (size_t)DIRS * BB * HH;
    const u16* hin = Hbuf + (size_t)(t & 1) * HSZ + (size_t)d * BB * HH;
    u16* hout      = Hbuf + (size_t)((t + 1) & 1) * HSZ + (size_t)d * BB * HH;
    int ubase = jj * 32 + nhalf * 16;

    f32x4 acc[4];
#pragma unroll
    for (int g = 0; g < 4; g++) acc[g] = fzero();

#pragma unroll
    for (int ks = 0; ks < 8; ks++) {
        int k0 = khalf * 256 + ks * 32;
        short8 a = *(const short8*)(hin + (size_t)(mtile * 16 + l15) * HH + k0 + quad * 8);
#pragma unroll
        for (int g = 0; g < 4; g++) {
            int n = g * 512 + ubase + l15;
            short8 bf = *(const short8*)(WT + ((size_t)d * 2048 + n) * 1024 + 512 + k0 + quad * 8);
            acc[g] = __builtin_amdgcn_mfma_f32_16x16x32_bf16(a, bf, acc[g], 0, 0, 0);
        }
    }

    __shared__ float red[2][2][4][4][64];   // 16 KB
    if (khalf == 1) {
#pragma unroll
        for (int g = 0; g < 4; g++)
#pragma unroll
            for (int r = 0; r < 4; r++) red[mtile][nhalf][g][r][lane] = acc[g][r];
    }
    __syncthreads();
    if (khalf == 0) {
#pragma unroll
        for (int g = 0; g < 4; g++)
#pragma unroll
            for (int r = 0; r < 4; r++) acc[g][r] += red[mtile][nhalf][g][r][lane];

        int u = ubase + l15;
#pragma unroll
        for (int r = 0; r < 4; r++) {
            int b = mtile * 16 + quad * 4 + r;
            int lb = lens[b];
            size_t pbase = (((size_t)d * chunk + tt) * BB + b) * FOURH;
            float zi = acc[0][r] + b2f(P[pbase + 0 * 512 + u]);
            float zj = acc[1][r] + b2f(P[pbase + 1 * 512 + u]);
            float zf = acc[2][r] + b2f(P[pbase + 2 * 512 + u]);
            float zo = acc[3][r] + b2f(P[pbase + 3 * 512 + u]);
            size_t cix = ((size_t)d * BB + b) * HH + u;
            float cold = Cst[cix];
            float cn = sigm(zf + 1.f) * cold + sigm(zi) * tanh_(zj);
            float hn = sigm(zo) * tanh_(cn);
            bool act = t < lb;
            float hprev = b2f(hin[(size_t)b * HH + u]);
            Cst[cix] = act ? cn : cold;
            hout[(size_t)b * HH + u] = f2b(act ? hn : hprev);
            int twr = isbw ? (act ? (lb - 1 - t) : t) : t;   // fused reverse_sequence scatter
            OUTS[(((size_t)s * BB + b) * TT + twr) * 1024 + isbw * 512 + u] = f2b(act ? hn : 0.f);
        }
    }
}

// ---------------------------------------------------------------------------
// K6: heads. logits[16384, 64] = U[16384, 5120] @ WBT^T + B64.
// ---------------------------------------------------------------------------
__global__ __launch_bounds__(256) void k_head(
    const u16* __restrict__ OUTS, const u16* __restrict__ WBT,
    const float* __restrict__ B64, float* __restrict__ OUT)
{
    int tid = threadIdx.x, w = tid >> 6, lane = tid & 63, quad = lane >> 4, l15 = lane & 15;
    int mtile = blockIdx.x * 4 + w, r0 = mtile * 16;
    int row_a = r0 + l15, ba = row_a >> 9, ta = row_a & 511;
    f32x4 acc[4];
#pragma unroll
    for (int ni = 0; ni < 4; ni++) acc[ni] = fzero();

    for (int k0 = 0; k0 < 5120; k0 += 32) {
        int kidx = k0 + quad * 8;
        int blkk = kidx >> 10, kk = kidx & 1023;
        short8 a = *(const short8*)(OUTS + (((size_t)blkk * BB + ba) * TT + ta) * 1024 + kk);
#pragma unroll
        for (int ni = 0; ni < 4; ni++) {
            short8 bf = *(const short8*)(WBT + (size_t)(ni * 16 + l15) * 5120 + kidx);
            acc[ni] = __builtin_amdgcn_mfma_f32_16x16x32_bf16(a, bf, acc[ni], 0, 0, 0);
        }
    }
#pragma unroll
    for (int ni = 0; ni < 4; ni++) {
        int c = ni * 16 + l15;
        float bv = B64[c];
#pragma unroll
        for (int r = 0; r < 4; r++) {
            int row = r0 + quad * 4 + r;
            OUT[(size_t)row * 64 + c] = acc[ni][r] + bv;
        }
    }
}

// ---------------------------------------------------------------------------
extern "C" void kernel_launch(void* const* d_in, const int* in_sizes, int n_in,
                              void* d_out, int out_size, void* d_ws, size_t ws_size,
                              hipStream_t stream) {
    const float* X   = (const float*)d_in[0];
    const int* lens  = (const int*)d_in[1];
    const float* Wf  = (const float*)d_in[2];
    const float* bf_ = (const float*)d_in[3];
    const float* Wb  = (const float*)d_in[4];
    const float* bb_ = (const float*)d_in[5];
    const float* W1  = (const float*)d_in[6];
    const float* b1  = (const float*)d_in[7];
    const float* W2  = (const float*)d_in[8];
    const float* b2  = (const float*)d_in[9];
    const float* W3  = (const float*)d_in[10];
    const float* b3  = (const float*)d_in[11];
    const float* W4  = (const float*)d_in[12];
    const float* b4  = (const float*)d_in[13];

    // ---- runtime workspace layout (round-0 crash diagnosis: never assume ws_size) ----
    char* ws = (char*)d_ws;
    size_t off = 0;
    auto take = [&](size_t bytes) { size_t o = off; off += (bytes + 255) & ~(size_t)255; return o; };
    size_t wtOff   = take((size_t)DIRS * 2048 * 1024 * 2);     // 41,943,040
    size_t xbOff   = take((size_t)BB * TT * DD * 2);           // 16,777,216
    size_t outsOff = take((size_t)5 * BB * TT * 1024 * 2);     // 167,772,160
    size_t hOff    = take((size_t)2 * DIRS * BB * HH * 2);     // 655,360
    size_t cOff    = take((size_t)DIRS * BB * HH * 4);         // 655,360
    size_t wbtOff  = take((size_t)64 * 5120 * 2);              // 655,360
    size_t b64Off  = take((size_t)64 * 4);                     // 256
    // elastic P chunk buffer: largest CHUNK in {64,32,16,8} that fits
    int chunk = 8;
    for (int c = 64; c >= 8; c >>= 1) {
        size_t pbytes = (size_t)DIRS * c * BB * FOURH * 2;
        if (off + pbytes <= ws_size) { chunk = c; break; }
    }
    size_t pOff = off;

    u16* WT    = (u16*)(ws + wtOff);
    u16* XB    = (u16*)(ws + xbOff);
    u16* P     = (u16*)(ws + pOff);
    u16* OUTS  = (u16*)(ws + outsOff);
    u16* Hbuf  = (u16*)(ws + hOff);
    float* Cst = (float*)(ws + cOff);
    u16* WBT   = (u16*)(ws + wbtOff);
    float* B64 = (float*)(ws + b64Off);

    // zero h ping-pong + c (H and C regions are adjacent)
    hipMemsetAsync(ws + hOff, 0, (size_t)(2 * DIRS * BB * HH * 2 + DIRS * BB * HH * 4), stream);

    k_convx<<<8192, 256, 0, stream>>>(X, XB);
    k_wt<<<dim3(32, 64, 10), 256, 0, stream>>>(Wf, Wb, WT);
    k_wbt<<<1280, 256, 0, stream>>>(W1, W2, W3, W4, b1, b2, b3, b4, WBT, B64);

    int nchunk = TT / chunk;
    for (int ch = 0; ch < nchunk; ch++) {
        k_pregemm<<<dim3(16, chunk / 4, 10), 256, 0, stream>>>(XB, WT, bf_, bb_, lens, P, ch * chunk, chunk);
        for (int q = 0; q < chunk; q++) {
            int t = ch * chunk + q;
            k_step<<<160, 512, 0, stream>>>(WT, P, Hbuf, Cst, OUTS, lens, t, q, chunk);
        }
    }
    k_head<<<256, 256, 0, stream>>>(OUTS, WBT, B64, (float*)d_out);
}